// Round 12
// baseline (219.635 us; speedup 1.0000x reference)
//
#include <hip/hip_runtime.h>
#include <hip/hip_bf16.h>

#define NQ 8192
#define NG 2048
#define CTX 64
#define DQ 512
#define DK 256
#define DV 256
#define DZ 256

typedef __attribute__((ext_vector_type(8))) short short8;
typedef __attribute__((ext_vector_type(4))) float f32x4;

__device__ __forceinline__ unsigned short f2bf_bits(float f) {
  __hip_bfloat16 h = __float2bfloat16(f);
  return __builtin_bit_cast(unsigned short, h);
}
__device__ __forceinline__ float bf2f(unsigned short u) {
  unsigned int x = ((unsigned int)u) << 16;
  return __builtin_bit_cast(float, x);
}
__device__ __forceinline__ void split2(float x, unsigned short& h, unsigned short& l) {
  h = f2bf_bits(x);
  l = f2bf_bits(x - bf2f(h));
}
__device__ __forceinline__ void cvt8_hl(f32x4 f0, f32x4 f1, short8& h8, short8& l8) {
#pragma unroll
  for (int j = 0; j < 4; j++) { unsigned short h, l; split2(f0[j], h, l); h8[j] = (short)h; l8[j] = (short)l; }
#pragma unroll
  for (int j = 0; j < 4; j++) { unsigned short h, l; split2(f1[j], h, l); h8[4 + j] = (short)h; l8[4 + j] = (short)l; }
}
__device__ __forceinline__ short8 cvt8_h(f32x4 f0, f32x4 f1) {
  short8 h8;
#pragma unroll
  for (int j = 0; j < 4; j++) h8[j] = (short)f2bf_bits(f0[j]);
#pragma unroll
  for (int j = 0; j < 4; j++) h8[4 + j] = (short)f2bf_bits(f1[j]);
  return h8;
}

// ---------------- prep: WqT split (transposed), Wk split (straight), starts, flag ----------------
__global__ void prep_kernel(const float* __restrict__ Wq, const float* __restrict__ Wk,
                            const int* __restrict__ gidx,
                            unsigned short* __restrict__ WqTh, unsigned short* __restrict__ WqTl,
                            unsigned short* __restrict__ Wkh, unsigned short* __restrict__ Wkl,
                            int* __restrict__ starts, int* __restrict__ mflag)
{
  int t = blockIdx.x * 256 + threadIdx.x;
  if (t < DZ * DQ) {                       // WqT*[z][kq] = Wq[kq][z]
    int z = t >> 9, kq = t & 511;
    unsigned short h, l; split2(Wq[(size_t)kq * DZ + z], h, l);
    WqTh[t] = h; WqTl[t] = l;
  } else if (t < DZ * DQ + DK * DZ) {      // Wk split in original layout [x][z]
    int u = t - DZ * DQ;
    unsigned short h, l; split2(Wk[u], h, l);
    Wkh[u] = h; Wkl[u] = l;
  } else if (t < DZ * DQ + DK * DZ + NG + 1) {
    int g = t - (DZ * DQ + DK * DZ);
    int lo = 0, hi = NQ;
    while (lo < hi) { int mid = (lo + hi) >> 1; if (gidx[mid] < g) lo = mid + 1; else hi = mid; }
    starts[g] = lo;
  } else if (t == DZ * DQ + DK * DZ + NG + 1) {
    mflag[0] = 0;
  }
}

// ---------------- mask dtype scan: flag=1 iff mask is 1-byte elements ----------------
__global__ void maskscan_kernel(const unsigned int* __restrict__ mw, int* __restrict__ flag)
{
  int i = blockIdx.x * 256 + threadIdx.x;
  unsigned int w = mw[i];
  bool bad = (w != 0u && w != 1u && w != 0x3F800000u);
  if (__any(bad) && ((threadIdx.x & 63) == 0))
    atomicOr(flag, 1);
}

// ---------------- qz = (q @ Wq + bq) * 1/16, stored as split bf16 pair ----------------
__global__ __launch_bounds__(256, 4) void qz_kernel(
    const float* __restrict__ q, const float* __restrict__ bq,
    const unsigned short* __restrict__ WqTh, const unsigned short* __restrict__ WqTl,
    unsigned short* __restrict__ qzh, unsigned short* __restrict__ qzl)
{
  const int tid = threadIdx.x;
  const int wave = tid >> 6, lane = tid & 63;
  const int i16 = lane & 15, hi4 = lane >> 4;
  const int mbase = blockIdx.x * 32;

  f32x4 acc[2][4];
#pragma unroll
  for (int a = 0; a < 2; a++)
#pragma unroll
    for (int b = 0; b < 4; b++) acc[a][b] = {0.f, 0.f, 0.f, 0.f};

  for (int kk = 0; kk < DQ; kk += 32) {
    f32x4 araw[2][2];
#pragma unroll
    for (int mt = 0; mt < 2; mt++) {
      const float* src = q + (size_t)(mbase + mt * 16 + i16) * DQ + kk + hi4 * 8;
      araw[mt][0] = *reinterpret_cast<const f32x4*>(src);
      araw[mt][1] = *reinterpret_cast<const f32x4*>(src + 4);
    }
    short8 ah[2], al[2];
#pragma unroll
    for (int mt = 0; mt < 2; mt++) cvt8_hl(araw[mt][0], araw[mt][1], ah[mt], al[mt]);

#pragma unroll
    for (int ntp = 0; ntp < 2; ntp++) {
      short8 bh[2], bl[2];
#pragma unroll
      for (int j = 0; j < 2; j++) {
        const int n = wave * 64 + (ntp * 2 + j) * 16 + i16;
        bh[j] = *reinterpret_cast<const short8*>(WqTh + (size_t)n * DQ + kk + hi4 * 8);
        bl[j] = *reinterpret_cast<const short8*>(WqTl + (size_t)n * DQ + kk + hi4 * 8);
      }
#pragma unroll
      for (int mt = 0; mt < 2; mt++)
#pragma unroll
        for (int j = 0; j < 2; j++) {
          f32x4 a = acc[mt][ntp * 2 + j];
          a = __builtin_amdgcn_mfma_f32_16x16x32_bf16(ah[mt], bh[j], a, 0, 0, 0);
          a = __builtin_amdgcn_mfma_f32_16x16x32_bf16(al[mt], bh[j], a, 0, 0, 0);
          a = __builtin_amdgcn_mfma_f32_16x16x32_bf16(ah[mt], bl[j], a, 0, 0, 0);
          acc[mt][ntp * 2 + j] = a;
        }
    }
  }

  const float scale = 0.0625f;
#pragma unroll
  for (int nt = 0; nt < 4; nt++) {
    const int n = wave * 64 + nt * 16 + i16;
    const float bias = bq[n];
#pragma unroll
    for (int mt = 0; mt < 2; mt++)
#pragma unroll
      for (int r = 0; r < 4; r++) {
        const int m = mbase + mt * 16 + hi4 * 4 + r;
        float x = (acc[mt][nt][r] + bias) * scale;
        unsigned short h, l; split2(x, h, l);
        qzh[(size_t)m * DZ + n] = h;
        qzl[(size_t)m * DZ + n] = l;
      }
  }
}

// ---------------- qk = qz @ Wk^T (3-term split), stored as split bf16 pair ----------------
__global__ __launch_bounds__(256, 4) void qk_kernel(
    const unsigned short* __restrict__ qzh, const unsigned short* __restrict__ qzl,
    const unsigned short* __restrict__ Wkh, const unsigned short* __restrict__ Wkl,
    unsigned short* __restrict__ qkh, unsigned short* __restrict__ qkl)
{
  const int tid = threadIdx.x;
  const int wave = tid >> 6, lane = tid & 63;
  const int i16 = lane & 15, hi4 = lane >> 4;
  const int mbase = blockIdx.x * 32;

  f32x4 acc[2][4];
#pragma unroll
  for (int a = 0; a < 2; a++)
#pragma unroll
    for (int b = 0; b < 4; b++) acc[a][b] = {0.f, 0.f, 0.f, 0.f};

#pragma unroll
  for (int kk = 0; kk < DZ; kk += 32) {
    short8 ah[2], al[2];
#pragma unroll
    for (int mt = 0; mt < 2; mt++) {
      ah[mt] = *reinterpret_cast<const short8*>(qzh + (size_t)(mbase + mt * 16 + i16) * DZ + kk + hi4 * 8);
      al[mt] = *reinterpret_cast<const short8*>(qzl + (size_t)(mbase + mt * 16 + i16) * DZ + kk + hi4 * 8);
    }
#pragma unroll
    for (int ntp = 0; ntp < 2; ntp++) {
      short8 bh[2], bl[2];
#pragma unroll
      for (int j = 0; j < 2; j++) {
        const int n = wave * 64 + (ntp * 2 + j) * 16 + i16;   // x index (row of Wk)
        bh[j] = *reinterpret_cast<const short8*>(Wkh + (size_t)n * DZ + kk + hi4 * 8);
        bl[j] = *reinterpret_cast<const short8*>(Wkl + (size_t)n * DZ + kk + hi4 * 8);
      }
#pragma unroll
      for (int mt = 0; mt < 2; mt++)
#pragma unroll
        for (int j = 0; j < 2; j++) {
          f32x4 a = acc[mt][ntp * 2 + j];
          a = __builtin_amdgcn_mfma_f32_16x16x32_bf16(ah[mt], bh[j], a, 0, 0, 0);
          a = __builtin_amdgcn_mfma_f32_16x16x32_bf16(al[mt], bh[j], a, 0, 0, 0);
          a = __builtin_amdgcn_mfma_f32_16x16x32_bf16(ah[mt], bl[j], a, 0, 0, 0);
          acc[mt][ntp * 2 + j] = a;
        }
    }
  }

#pragma unroll
  for (int nt = 0; nt < 4; nt++) {
    const int n = wave * 64 + nt * 16 + i16;
#pragma unroll
    for (int mt = 0; mt < 2; mt++)
#pragma unroll
      for (int r = 0; r < 4; r++) {
        const int mrow = mbase + mt * 16 + hi4 * 4 + r;
        unsigned short h, l; split2(acc[mt][nt][r], h, l);
        qkh[(size_t)mrow * DK + n] = h;
        qkl[(size_t)mrow * DK + n] = l;
      }
  }
}

// ---------------- attn v5: block/group, NO k-LDS (global k per chunk), per-wave stride-18
// P-LDS (zero bank conflicts, zero barriers), v in regs, mbits mask ----------------
// S layout: lane (q=q16, h), reg (mt,r) holds S[l=16mt+4h+r][q].
// PV A-frag elem j (kt): P[l=32kt+8h+j][q16] <- p_lds read, conflict-free at stride 18.
__global__ __launch_bounds__(256, 3) void attn_v5_kernel(
    const float* __restrict__ kmat, const float* __restrict__ vmat,
    const void* __restrict__ mmask, const int* __restrict__ mflagp,
    const int* __restrict__ starts,
    const unsigned short* __restrict__ qkh, const unsigned short* __restrict__ qkl,
    float* __restrict__ out)
{
  const int g = blockIdx.x;
  const int q0 = starts[g], q1 = starts[g + 1];
  if (q0 >= q1) return;

  const int tid = threadIdx.x;
  const int wave = tid >> 6, lane = tid & 63;
  const int q16 = lane & 15, h = lane >> 4;

  __shared__ __align__(16) unsigned short p_lds[4][2][CTX * 18];  // 18,432 B; per-wave private

  unsigned short* php = &p_lds[wave][0][0];
  unsigned short* plp = &p_lds[wave][1][0];

  // ---- mask bitmask: bit (mt*4+r) = valid(l = 16mt + 4h + r)
  unsigned int mbits = 0;
  const int mfl = mflagp[0];
#pragma unroll
  for (int mt = 0; mt < 4; mt++)
#pragma unroll
    for (int r = 0; r < 4; r++) {
      const int l = mt * 16 + 4 * h + r;
      bool valid;
      if (mfl) valid = ((const unsigned char*)mmask)[(size_t)g * CTX + l] != 0;
      else     valid = ((const unsigned int*)mmask)[(size_t)g * CTX + l] != 0u;
      mbits |= (valid ? 1u : 0u) << (mt * 4 + r);
    }

  // ---- preload v slice to regs (chunk-invariant, d-split across waves)
  const float* vg = vmat + (size_t)g * (CTX * DV);
  short8 vb[2][4];
#pragma unroll
  for (int kt = 0; kt < 2; kt++)
#pragma unroll
    for (int nt = 0; nt < 4; nt++) {
      const int d = wave * 64 + nt * 16 + q16;
      const float* vcol = vg + (size_t)(kt * 32 + h * 8) * DV + d;
      short8 t;
#pragma unroll
      for (int j = 0; j < 8; j++) t[j] = (short)f2bf_bits(vcol[(size_t)j * DV]);
      vb[kt][nt] = t;
    }

  const float* kg = kmat + (size_t)g * (CTX * DK);
  const int nchunks = (q1 - q0 + 15) >> 4;

  for (int c = 0; c < nchunks; c++) {
    const int qbase = q0 + c * 16;
    int qrow = qbase + q16; if (qrow > NQ - 1) qrow = NQ - 1;   // clamp, masked at store
    const unsigned short* qh_p = qkh + (size_t)qrow * DK;
    const unsigned short* ql_p = qkl + (size_t)qrow * DK;

    // ---- S: k streamed from global (L2-hot across the block's 4 waves), qk per kk
    f32x4 accs[4];
#pragma unroll
    for (int mt = 0; mt < 4; mt++) accs[mt] = {0.f, 0.f, 0.f, 0.f};
#pragma unroll
    for (int kk = 0; kk < 8; kk++) {
      short8 bfh = *reinterpret_cast<const short8*>(qh_p + kk * 32 + h * 8);
      short8 bfl = *reinterpret_cast<const short8*>(ql_p + kk * 32 + h * 8);
      short8 kf[4];
#pragma unroll
      for (int mt = 0; mt < 4; mt++) {
        const float* rowp = kg + (size_t)(mt * 16 + q16) * DK + kk * 32 + h * 8;
        f32x4 f0 = *reinterpret_cast<const f32x4*>(rowp);
        f32x4 f1 = *reinterpret_cast<const f32x4*>(rowp + 4);
        kf[mt] = cvt8_h(f0, f1);
      }
#pragma unroll
      for (int mt = 0; mt < 4; mt++) {
        accs[mt] = __builtin_amdgcn_mfma_f32_16x16x32_bf16(kf[mt], bfh, accs[mt], 0, 0, 0);
        accs[mt] = __builtin_amdgcn_mfma_f32_16x16x32_bf16(kf[mt], bfl, accs[mt], 0, 0, 0);
      }
    }

    // ---- mask + softmax over l (16 in-lane + cross-h via shfl_xor 16/32)
    float mx = -3.0e38f;
#pragma unroll
    for (int mt = 0; mt < 4; mt++)
#pragma unroll
      for (int r = 0; r < 4; r++) {
        float s = accs[mt][r] + (((mbits >> (mt * 4 + r)) & 1u) ? 0.0f : -1e30f);
        accs[mt][r] = s;
        mx = fmaxf(mx, s);
      }
    mx = fmaxf(mx, __shfl_xor(mx, 16));
    mx = fmaxf(mx, __shfl_xor(mx, 32));
    float sum = 0.f;
#pragma unroll
    for (int mt = 0; mt < 4; mt++)
#pragma unroll
      for (int r = 0; r < 4; r++) {
        float p = __expf(accs[mt][r] - mx);
        accs[mt][r] = p;
        sum += p;
      }
    sum += __shfl_xor(sum, 16);
    sum += __shfl_xor(sum, 32);
    const float inv = 1.0f / sum;

    // ---- P -> per-wave LDS (stride 18: write 2-way max, read conflict-free); no barriers
#pragma unroll
    for (int mt = 0; mt < 4; mt++)
#pragma unroll
      for (int r = 0; r < 4; r++) {
        const int l = mt * 16 + 4 * h + r;
        unsigned short hh, ll; split2(accs[mt][r] * inv, hh, ll);
        php[l * 18 + q16] = hh;
        plp[l * 18 + q16] = ll;
      }

    // ---- PV A-fragments from LDS
    short8 pah[2], pal[2];
#pragma unroll
    for (int kt = 0; kt < 2; kt++)
#pragma unroll
      for (int j = 0; j < 8; j++) {
        const int l = kt * 32 + h * 8 + j;
        pah[kt][j] = (short)php[l * 18 + q16];
        pal[kt][j] = (short)plp[l * 18 + q16];
      }

    // ---- PV with v in regs
    f32x4 acco[4];
#pragma unroll
    for (int nt = 0; nt < 4; nt++) acco[nt] = {0.f, 0.f, 0.f, 0.f};
#pragma unroll
    for (int kt = 0; kt < 2; kt++)
#pragma unroll
      for (int nt = 0; nt < 4; nt++) {
        acco[nt] = __builtin_amdgcn_mfma_f32_16x16x32_bf16(pah[kt], vb[kt][nt], acco[nt], 0, 0, 0);
        acco[nt] = __builtin_amdgcn_mfma_f32_16x16x32_bf16(pal[kt], vb[kt][nt], acco[nt], 0, 0, 0);
      }

#pragma unroll
    for (int nt = 0; nt < 4; nt++) {
      const int d = wave * 64 + nt * 16 + q16;
#pragma unroll
      for (int r = 0; r < 4; r++) {
        const int qrow2 = qbase + h * 4 + r;
        if (qrow2 < q1)
          out[(size_t)qrow2 * DV + d] = acco[nt][r];
      }
    }
  }
}

extern "C" void kernel_launch(void* const* d_in, const int* in_sizes, int n_in,
                              void* d_out, int out_size, void* d_ws, size_t ws_size,
                              hipStream_t stream) {
  const float* q  = (const float*)d_in[0];
  const float* k  = (const float*)d_in[1];
  const float* v  = (const float*)d_in[2];
  const void*  m  = d_in[3];
  const int* gidx = (const int*)d_in[4];
  const float* Wq = (const float*)d_in[5];
  const float* bq = (const float*)d_in[6];
  const float* Wk = (const float*)d_in[7];   // bk dropped: per-query constant cancels in softmax
  float* out = (float*)d_out;

  char* ws = (char*)d_ws;
  unsigned short* qzh  = (unsigned short*)(ws);                   // 4 MB
  unsigned short* qzl  = (unsigned short*)(ws + 4194304);         // 4 MB
  unsigned short* qkh  = (unsigned short*)(ws + 8388608);         // 4 MB
  unsigned short* qkl  = (unsigned short*)(ws + 12582912);        // 4 MB
  unsigned short* WqTh = (unsigned short*)(ws + 16777216);        // 256 KB
  unsigned short* WqTl = (unsigned short*)(ws + 17039360);        // 256 KB
  unsigned short* Wkh  = (unsigned short*)(ws + 17301504);        // 128 KB
  unsigned short* Wkl  = (unsigned short*)(ws + 17432576);        // 128 KB
  int* starts          = (int*)(ws + 17563648);                   // 2049*4
  int* mflag           = (int*)(ws + 17571844);                   // 4 B

  hipLaunchKernelGGL(prep_kernel, dim3(777), dim3(256), 0, stream,
                     Wq, Wk, gidx, WqTh, WqTl, Wkh, Wkl, starts, mflag);
  hipLaunchKernelGGL(maskscan_kernel, dim3(128), dim3(256), 0, stream,
                     (const unsigned int*)m, mflag);
  hipLaunchKernelGGL(qz_kernel, dim3(NQ / 32), dim3(256), 0, stream,
                     q, bq, WqTh, WqTl, qzh, qzl);
  hipLaunchKernelGGL(qk_kernel, dim3(NQ / 32), dim3(256), 0, stream,
                     qzh, qzl, Wkh, Wkl, qkh, qkl);
  hipLaunchKernelGGL(attn_v5_kernel, dim3(NG), dim3(256), 0, stream,
                     k, v, m, (const int*)mflag, starts, qkh, qkl, out);
}

// Round 13
// 179.704 us; speedup vs baseline: 1.2222x; 1.2222x over previous
//
#include <hip/hip_runtime.h>
#include <hip/hip_bf16.h>

#define NQ 8192
#define NG 2048
#define CTX 64
#define DQ 512
#define DK 256
#define DV 256
#define DZ 256

typedef __attribute__((ext_vector_type(8))) short short8;
typedef __attribute__((ext_vector_type(4))) float f32x4;

__device__ __forceinline__ unsigned short f2bf_bits(float f) {
  __hip_bfloat16 h = __float2bfloat16(f);
  return __builtin_bit_cast(unsigned short, h);
}
__device__ __forceinline__ float bf2f(unsigned short u) {
  unsigned int x = ((unsigned int)u) << 16;
  return __builtin_bit_cast(float, x);
}
__device__ __forceinline__ void split2(float x, unsigned short& h, unsigned short& l) {
  h = f2bf_bits(x);
  l = f2bf_bits(x - bf2f(h));
}
__device__ __forceinline__ void cvt8_hl(f32x4 f0, f32x4 f1, short8& h8, short8& l8) {
#pragma unroll
  for (int j = 0; j < 4; j++) { unsigned short h, l; split2(f0[j], h, l); h8[j] = (short)h; l8[j] = (short)l; }
#pragma unroll
  for (int j = 0; j < 4; j++) { unsigned short h, l; split2(f1[j], h, l); h8[4 + j] = (short)h; l8[4 + j] = (short)l; }
}
__device__ __forceinline__ short8 cvt8_h(f32x4 f0, f32x4 f1) {
  short8 h8;
#pragma unroll
  for (int j = 0; j < 4; j++) h8[j] = (short)f2bf_bits(f0[j]);
#pragma unroll
  for (int j = 0; j < 4; j++) h8[4 + j] = (short)f2bf_bits(f1[j]);
  return h8;
}

// ---------------- prep: WqT split (transposed), Wk split (straight), starts, flag ----------------
__global__ void prep_kernel(const float* __restrict__ Wq, const float* __restrict__ Wk,
                            const int* __restrict__ gidx,
                            unsigned short* __restrict__ WqTh, unsigned short* __restrict__ WqTl,
                            unsigned short* __restrict__ Wkh, unsigned short* __restrict__ Wkl,
                            int* __restrict__ starts, int* __restrict__ mflag)
{
  int t = blockIdx.x * 256 + threadIdx.x;
  if (t < DZ * DQ) {                       // WqT*[z][kq] = Wq[kq][z]
    int z = t >> 9, kq = t & 511;
    unsigned short h, l; split2(Wq[(size_t)kq * DZ + z], h, l);
    WqTh[t] = h; WqTl[t] = l;
  } else if (t < DZ * DQ + DK * DZ) {      // Wk split in original layout [x][z]
    int u = t - DZ * DQ;
    unsigned short h, l; split2(Wk[u], h, l);
    Wkh[u] = h; Wkl[u] = l;
  } else if (t < DZ * DQ + DK * DZ + NG + 1) {
    int g = t - (DZ * DQ + DK * DZ);
    int lo = 0, hi = NQ;
    while (lo < hi) { int mid = (lo + hi) >> 1; if (gidx[mid] < g) lo = mid + 1; else hi = mid; }
    starts[g] = lo;
  } else if (t == DZ * DQ + DK * DZ + NG + 1) {
    mflag[0] = 0;
  }
}

// ---------------- mask dtype scan: flag=1 iff mask is 1-byte elements ----------------
__global__ void maskscan_kernel(const unsigned int* __restrict__ mw, int* __restrict__ flag)
{
  int i = blockIdx.x * 256 + threadIdx.x;
  unsigned int w = mw[i];
  bool bad = (w != 0u && w != 1u && w != 0x3F800000u);
  if (__any(bad) && ((threadIdx.x & 63) == 0))
    atomicOr(flag, 1);
}

// ---------------- qz = (q @ Wq + bq) * 1/16, stored as split bf16 pair ----------------
__global__ __launch_bounds__(256, 4) void qz_kernel(
    const float* __restrict__ q, const float* __restrict__ bq,
    const unsigned short* __restrict__ WqTh, const unsigned short* __restrict__ WqTl,
    unsigned short* __restrict__ qzh, unsigned short* __restrict__ qzl)
{
  const int tid = threadIdx.x;
  const int wave = tid >> 6, lane = tid & 63;
  const int i16 = lane & 15, hi4 = lane >> 4;
  const int mbase = blockIdx.x * 32;

  f32x4 acc[2][4];
#pragma unroll
  for (int a = 0; a < 2; a++)
#pragma unroll
    for (int b = 0; b < 4; b++) acc[a][b] = {0.f, 0.f, 0.f, 0.f};

  for (int kk = 0; kk < DQ; kk += 32) {
    f32x4 araw[2][2];
#pragma unroll
    for (int mt = 0; mt < 2; mt++) {
      const float* src = q + (size_t)(mbase + mt * 16 + i16) * DQ + kk + hi4 * 8;
      araw[mt][0] = *reinterpret_cast<const f32x4*>(src);
      araw[mt][1] = *reinterpret_cast<const f32x4*>(src + 4);
    }
    short8 ah[2], al[2];
#pragma unroll
    for (int mt = 0; mt < 2; mt++) cvt8_hl(araw[mt][0], araw[mt][1], ah[mt], al[mt]);

#pragma unroll
    for (int ntp = 0; ntp < 2; ntp++) {
      short8 bh[2], bl[2];
#pragma unroll
      for (int j = 0; j < 2; j++) {
        const int n = wave * 64 + (ntp * 2 + j) * 16 + i16;
        bh[j] = *reinterpret_cast<const short8*>(WqTh + (size_t)n * DQ + kk + hi4 * 8);
        bl[j] = *reinterpret_cast<const short8*>(WqTl + (size_t)n * DQ + kk + hi4 * 8);
      }
#pragma unroll
      for (int mt = 0; mt < 2; mt++)
#pragma unroll
        for (int j = 0; j < 2; j++) {
          f32x4 a = acc[mt][ntp * 2 + j];
          a = __builtin_amdgcn_mfma_f32_16x16x32_bf16(ah[mt], bh[j], a, 0, 0, 0);
          a = __builtin_amdgcn_mfma_f32_16x16x32_bf16(al[mt], bh[j], a, 0, 0, 0);
          a = __builtin_amdgcn_mfma_f32_16x16x32_bf16(ah[mt], bl[j], a, 0, 0, 0);
          acc[mt][ntp * 2 + j] = a;
        }
    }
  }

  const float scale = 0.0625f;
#pragma unroll
  for (int nt = 0; nt < 4; nt++) {
    const int n = wave * 64 + nt * 16 + i16;
    const float bias = bq[n];
#pragma unroll
    for (int mt = 0; mt < 2; mt++)
#pragma unroll
      for (int r = 0; r < 4; r++) {
        const int m = mbase + mt * 16 + hi4 * 4 + r;
        float x = (acc[mt][nt][r] + bias) * scale;
        unsigned short h, l; split2(x, h, l);
        qzh[(size_t)m * DZ + n] = h;
        qzl[(size_t)m * DZ + n] = l;
      }
  }
}

// ---------------- qk = qz @ Wk^T (3-term split), stored as split bf16 pair ----------------
__global__ __launch_bounds__(256, 4) void qk_kernel(
    const unsigned short* __restrict__ qzh, const unsigned short* __restrict__ qzl,
    const unsigned short* __restrict__ Wkh, const unsigned short* __restrict__ Wkl,
    unsigned short* __restrict__ qkh, unsigned short* __restrict__ qkl)
{
  const int tid = threadIdx.x;
  const int wave = tid >> 6, lane = tid & 63;
  const int i16 = lane & 15, hi4 = lane >> 4;
  const int mbase = blockIdx.x * 32;

  f32x4 acc[2][4];
#pragma unroll
  for (int a = 0; a < 2; a++)
#pragma unroll
    for (int b = 0; b < 4; b++) acc[a][b] = {0.f, 0.f, 0.f, 0.f};

#pragma unroll
  for (int kk = 0; kk < DZ; kk += 32) {
    short8 ah[2], al[2];
#pragma unroll
    for (int mt = 0; mt < 2; mt++) {
      ah[mt] = *reinterpret_cast<const short8*>(qzh + (size_t)(mbase + mt * 16 + i16) * DZ + kk + hi4 * 8);
      al[mt] = *reinterpret_cast<const short8*>(qzl + (size_t)(mbase + mt * 16 + i16) * DZ + kk + hi4 * 8);
    }
#pragma unroll
    for (int ntp = 0; ntp < 2; ntp++) {
      short8 bh[2], bl[2];
#pragma unroll
      for (int j = 0; j < 2; j++) {
        const int n = wave * 64 + (ntp * 2 + j) * 16 + i16;   // x index (row of Wk)
        bh[j] = *reinterpret_cast<const short8*>(Wkh + (size_t)n * DZ + kk + hi4 * 8);
        bl[j] = *reinterpret_cast<const short8*>(Wkl + (size_t)n * DZ + kk + hi4 * 8);
      }
#pragma unroll
      for (int mt = 0; mt < 2; mt++)
#pragma unroll
        for (int j = 0; j < 2; j++) {
          f32x4 a = acc[mt][ntp * 2 + j];
          a = __builtin_amdgcn_mfma_f32_16x16x32_bf16(ah[mt], bh[j], a, 0, 0, 0);
          a = __builtin_amdgcn_mfma_f32_16x16x32_bf16(al[mt], bh[j], a, 0, 0, 0);
          a = __builtin_amdgcn_mfma_f32_16x16x32_bf16(ah[mt], bl[j], a, 0, 0, 0);
          acc[mt][ntp * 2 + j] = a;
        }
    }
  }

#pragma unroll
  for (int nt = 0; nt < 4; nt++) {
    const int n = wave * 64 + nt * 16 + i16;
#pragma unroll
    for (int mt = 0; mt < 2; mt++)
#pragma unroll
      for (int r = 0; r < 4; r++) {
        const int mrow = mbase + mt * 16 + hi4 * 4 + r;
        unsigned short h, l; split2(acc[mt][nt][r], h, l);
        qkh[(size_t)mrow * DK + n] = h;
        qkl[(size_t)mrow * DK + n] = l;
      }
  }
}

// ---------------- attn v6: IDENTICAL to v5 except __launch_bounds__(256) (no min-waves arg).
// Theory: on this toolchain the 2nd arg caps VGPR at ~512/(2*arg) and force-spills
// ((256,4)->64, (256,3)->84 observed); single-arg form lets the allocator fit the
// live set (R2 precedent: 160 VGPR, zero spill). ----------------
__global__ __launch_bounds__(256) void attn_v6_kernel(
    const float* __restrict__ kmat, const float* __restrict__ vmat,
    const void* __restrict__ mmask, const int* __restrict__ mflagp,
    const int* __restrict__ starts,
    const unsigned short* __restrict__ qkh, const unsigned short* __restrict__ qkl,
    float* __restrict__ out)
{
  const int g = blockIdx.x;
  const int q0 = starts[g], q1 = starts[g + 1];
  if (q0 >= q1) return;

  const int tid = threadIdx.x;
  const int wave = tid >> 6, lane = tid & 63;
  const int q16 = lane & 15, h = lane >> 4;

  __shared__ __align__(16) unsigned short p_lds[4][2][CTX * 18];  // 18,432 B; per-wave private

  unsigned short* php = &p_lds[wave][0][0];
  unsigned short* plp = &p_lds[wave][1][0];

  // ---- mask bitmask: bit (mt*4+r) = valid(l = 16mt + 4h + r)
  unsigned int mbits = 0;
  const int mfl = mflagp[0];
#pragma unroll
  for (int mt = 0; mt < 4; mt++)
#pragma unroll
    for (int r = 0; r < 4; r++) {
      const int l = mt * 16 + 4 * h + r;
      bool valid;
      if (mfl) valid = ((const unsigned char*)mmask)[(size_t)g * CTX + l] != 0;
      else     valid = ((const unsigned int*)mmask)[(size_t)g * CTX + l] != 0u;
      mbits |= (valid ? 1u : 0u) << (mt * 4 + r);
    }

  // ---- preload v slice to regs (chunk-invariant, d-split across waves)
  const float* vg = vmat + (size_t)g * (CTX * DV);
  short8 vb[2][4];
#pragma unroll
  for (int kt = 0; kt < 2; kt++)
#pragma unroll
    for (int nt = 0; nt < 4; nt++) {
      const int d = wave * 64 + nt * 16 + q16;
      const float* vcol = vg + (size_t)(kt * 32 + h * 8) * DV + d;
      short8 t;
#pragma unroll
      for (int j = 0; j < 8; j++) t[j] = (short)f2bf_bits(vcol[(size_t)j * DV]);
      vb[kt][nt] = t;
    }

  const float* kg = kmat + (size_t)g * (CTX * DK);
  const int nchunks = (q1 - q0 + 15) >> 4;

  for (int c = 0; c < nchunks; c++) {
    const int qbase = q0 + c * 16;
    int qrow = qbase + q16; if (qrow > NQ - 1) qrow = NQ - 1;   // clamp, masked at store
    const unsigned short* qh_p = qkh + (size_t)qrow * DK;
    const unsigned short* ql_p = qkl + (size_t)qrow * DK;

    // ---- S: k streamed from global (L2-hot across the block's 4 waves), qk per kk
    f32x4 accs[4];
#pragma unroll
    for (int mt = 0; mt < 4; mt++) accs[mt] = {0.f, 0.f, 0.f, 0.f};
#pragma unroll
    for (int kk = 0; kk < 8; kk++) {
      short8 bfh = *reinterpret_cast<const short8*>(qh_p + kk * 32 + h * 8);
      short8 bfl = *reinterpret_cast<const short8*>(ql_p + kk * 32 + h * 8);
      short8 kf[4];
#pragma unroll
      for (int mt = 0; mt < 4; mt++) {
        const float* rowp = kg + (size_t)(mt * 16 + q16) * DK + kk * 32 + h * 8;
        f32x4 f0 = *reinterpret_cast<const f32x4*>(rowp);
        f32x4 f1 = *reinterpret_cast<const f32x4*>(rowp + 4);
        kf[mt] = cvt8_h(f0, f1);
      }
#pragma unroll
      for (int mt = 0; mt < 4; mt++) {
        accs[mt] = __builtin_amdgcn_mfma_f32_16x16x32_bf16(kf[mt], bfh, accs[mt], 0, 0, 0);
        accs[mt] = __builtin_amdgcn_mfma_f32_16x16x32_bf16(kf[mt], bfl, accs[mt], 0, 0, 0);
      }
    }

    // ---- mask + softmax over l (16 in-lane + cross-h via shfl_xor 16/32)
    float mx = -3.0e38f;
#pragma unroll
    for (int mt = 0; mt < 4; mt++)
#pragma unroll
      for (int r = 0; r < 4; r++) {
        float s = accs[mt][r] + (((mbits >> (mt * 4 + r)) & 1u) ? 0.0f : -1e30f);
        accs[mt][r] = s;
        mx = fmaxf(mx, s);
      }
    mx = fmaxf(mx, __shfl_xor(mx, 16));
    mx = fmaxf(mx, __shfl_xor(mx, 32));
    float sum = 0.f;
#pragma unroll
    for (int mt = 0; mt < 4; mt++)
#pragma unroll
      for (int r = 0; r < 4; r++) {
        float p = __expf(accs[mt][r] - mx);
        accs[mt][r] = p;
        sum += p;
      }
    sum += __shfl_xor(sum, 16);
    sum += __shfl_xor(sum, 32);
    const float inv = 1.0f / sum;

    // ---- P -> per-wave LDS (stride 18: write 2-way max, read conflict-free); no barriers
#pragma unroll
    for (int mt = 0; mt < 4; mt++)
#pragma unroll
      for (int r = 0; r < 4; r++) {
        const int l = mt * 16 + 4 * h + r;
        unsigned short hh, ll; split2(accs[mt][r] * inv, hh, ll);
        php[l * 18 + q16] = hh;
        plp[l * 18 + q16] = ll;
      }

    // ---- PV A-fragments from LDS
    short8 pah[2], pal[2];
#pragma unroll
    for (int kt = 0; kt < 2; kt++)
#pragma unroll
      for (int j = 0; j < 8; j++) {
        const int l = kt * 32 + h * 8 + j;
        pah[kt][j] = (short)php[l * 18 + q16];
        pal[kt][j] = (short)plp[l * 18 + q16];
      }

    // ---- PV with v in regs
    f32x4 acco[4];
#pragma unroll
    for (int nt = 0; nt < 4; nt++) acco[nt] = {0.f, 0.f, 0.f, 0.f};
#pragma unroll
    for (int kt = 0; kt < 2; kt++)
#pragma unroll
      for (int nt = 0; nt < 4; nt++) {
        acco[nt] = __builtin_amdgcn_mfma_f32_16x16x32_bf16(pah[kt], vb[kt][nt], acco[nt], 0, 0, 0);
        acco[nt] = __builtin_amdgcn_mfma_f32_16x16x32_bf16(pal[kt], vb[kt][nt], acco[nt], 0, 0, 0);
      }

#pragma unroll
    for (int nt = 0; nt < 4; nt++) {
      const int d = wave * 64 + nt * 16 + q16;
#pragma unroll
      for (int r = 0; r < 4; r++) {
        const int qrow2 = qbase + h * 4 + r;
        if (qrow2 < q1)
          out[(size_t)qrow2 * DV + d] = acco[nt][r];
      }
    }
  }
}

extern "C" void kernel_launch(void* const* d_in, const int* in_sizes, int n_in,
                              void* d_out, int out_size, void* d_ws, size_t ws_size,
                              hipStream_t stream) {
  const float* q  = (const float*)d_in[0];
  const float* k  = (const float*)d_in[1];
  const float* v  = (const float*)d_in[2];
  const void*  m  = d_in[3];
  const int* gidx = (const int*)d_in[4];
  const float* Wq = (const float*)d_in[5];
  const float* bq = (const float*)d_in[6];
  const float* Wk = (const float*)d_in[7];   // bk dropped: per-query constant cancels in softmax
  float* out = (float*)d_out;

  char* ws = (char*)d_ws;
  unsigned short* qzh  = (unsigned short*)(ws);                   // 4 MB
  unsigned short* qzl  = (unsigned short*)(ws + 4194304);         // 4 MB
  unsigned short* qkh  = (unsigned short*)(ws + 8388608);         // 4 MB
  unsigned short* qkl  = (unsigned short*)(ws + 12582912);        // 4 MB
  unsigned short* WqTh = (unsigned short*)(ws + 16777216);        // 256 KB
  unsigned short* WqTl = (unsigned short*)(ws + 17039360);        // 256 KB
  unsigned short* Wkh  = (unsigned short*)(ws + 17301504);        // 128 KB
  unsigned short* Wkl  = (unsigned short*)(ws + 17432576);        // 128 KB
  int* starts          = (int*)(ws + 17563648);                   // 2049*4
  int* mflag           = (int*)(ws + 17571844);                   // 4 B

  hipLaunchKernelGGL(prep_kernel, dim3(777), dim3(256), 0, stream,
                     Wq, Wk, gidx, WqTh, WqTl, Wkh, Wkl, starts, mflag);
  hipLaunchKernelGGL(maskscan_kernel, dim3(128), dim3(256), 0, stream,
                     (const unsigned int*)m, mflag);
  hipLaunchKernelGGL(qz_kernel, dim3(NQ / 32), dim3(256), 0, stream,
                     q, bq, WqTh, WqTl, qzh, qzl);
  hipLaunchKernelGGL(qk_kernel, dim3(NQ / 32), dim3(256), 0, stream,
                     qzh, qzl, Wkh, Wkl, qkh, qkl);
  hipLaunchKernelGGL(attn_v6_kernel, dim3(NG), dim3(256), 0, stream,
                     k, v, m, (const int*)mflag, starts, qkh, qkl, out);
}

// Round 14
// 125.176 us; speedup vs baseline: 1.7546x; 1.4356x over previous
//
#include <hip/hip_runtime.h>
#include <hip/hip_bf16.h>

#define NQ 8192
#define NG 2048
#define CTX 64
#define DQ 512
#define DK 256
#define DV 256
#define DZ 256

typedef __attribute__((ext_vector_type(8))) short short8;
typedef __attribute__((ext_vector_type(4))) float f32x4;
typedef __attribute__((ext_vector_type(4))) unsigned int u32x4;

__device__ __forceinline__ unsigned short f2bf_bits(float f) {
  __hip_bfloat16 h = __float2bfloat16(f);
  return __builtin_bit_cast(unsigned short, h);
}
__device__ __forceinline__ float bf2f(unsigned short u) {
  unsigned int x = ((unsigned int)u) << 16;
  return __builtin_bit_cast(float, x);
}
__device__ __forceinline__ void split2(float x, unsigned short& h, unsigned short& l) {
  h = f2bf_bits(x);
  l = f2bf_bits(x - bf2f(h));
}
__device__ __forceinline__ void cvt8_hl(f32x4 f0, f32x4 f1, short8& h8, short8& l8) {
#pragma unroll
  for (int j = 0; j < 4; j++) { unsigned short h, l; split2(f0[j], h, l); h8[j] = (short)h; l8[j] = (short)l; }
#pragma unroll
  for (int j = 0; j < 4; j++) { unsigned short h, l; split2(f1[j], h, l); h8[4 + j] = (short)h; l8[4 + j] = (short)l; }
}
__device__ __forceinline__ short8 cvt8_h(f32x4 f0, f32x4 f1) {
  short8 h8;
#pragma unroll
  for (int j = 0; j < 4; j++) h8[j] = (short)f2bf_bits(f0[j]);
#pragma unroll
  for (int j = 0; j < 4; j++) h8[4 + j] = (short)f2bf_bits(f1[j]);
  return h8;
}

// ---------------- prep: WqT split (transposed), Wk split (straight), starts, flag ----------------
__global__ void prep_kernel(const float* __restrict__ Wq, const float* __restrict__ Wk,
                            const int* __restrict__ gidx,
                            unsigned short* __restrict__ WqTh, unsigned short* __restrict__ WqTl,
                            unsigned short* __restrict__ Wkh, unsigned short* __restrict__ Wkl,
                            int* __restrict__ starts, int* __restrict__ mflag)
{
  int t = blockIdx.x * 256 + threadIdx.x;
  if (t < DZ * DQ) {                       // WqT*[z][kq] = Wq[kq][z]
    int z = t >> 9, kq = t & 511;
    unsigned short h, l; split2(Wq[(size_t)kq * DZ + z], h, l);
    WqTh[t] = h; WqTl[t] = l;
  } else if (t < DZ * DQ + DK * DZ) {      // Wk split in original layout [x][z]
    int u = t - DZ * DQ;
    unsigned short h, l; split2(Wk[u], h, l);
    Wkh[u] = h; Wkl[u] = l;
  } else if (t < DZ * DQ + DK * DZ + NG + 1) {
    int g = t - (DZ * DQ + DK * DZ);
    int lo = 0, hi = NQ;
    while (lo < hi) { int mid = (lo + hi) >> 1; if (gidx[mid] < g) lo = mid + 1; else hi = mid; }
    starts[g] = lo;
  } else if (t == DZ * DQ + DK * DZ + NG + 1) {
    mflag[0] = 0;
  }
}

// ---------------- mask dtype scan: flag=1 iff mask is 1-byte elements ----------------
__global__ void maskscan_kernel(const unsigned int* __restrict__ mw, int* __restrict__ flag)
{
  int i = blockIdx.x * 256 + threadIdx.x;
  unsigned int w = mw[i];
  bool bad = (w != 0u && w != 1u && w != 0x3F800000u);
  if (__any(bad) && ((threadIdx.x & 63) == 0))
    atomicOr(flag, 1);
}

// ---------------- qz = (q @ Wq + bq) * 1/16, stored as split bf16 pair ----------------
__global__ __launch_bounds__(256, 4) void qz_kernel(
    const float* __restrict__ q, const float* __restrict__ bq,
    const unsigned short* __restrict__ WqTh, const unsigned short* __restrict__ WqTl,
    unsigned short* __restrict__ qzh, unsigned short* __restrict__ qzl)
{
  const int tid = threadIdx.x;
  const int wave = tid >> 6, lane = tid & 63;
  const int i16 = lane & 15, hi4 = lane >> 4;
  const int mbase = blockIdx.x * 32;

  f32x4 acc[2][4];
#pragma unroll
  for (int a = 0; a < 2; a++)
#pragma unroll
    for (int b = 0; b < 4; b++) acc[a][b] = {0.f, 0.f, 0.f, 0.f};

  for (int kk = 0; kk < DQ; kk += 32) {
    f32x4 araw[2][2];
#pragma unroll
    for (int mt = 0; mt < 2; mt++) {
      const float* src = q + (size_t)(mbase + mt * 16 + i16) * DQ + kk + hi4 * 8;
      araw[mt][0] = *reinterpret_cast<const f32x4*>(src);
      araw[mt][1] = *reinterpret_cast<const f32x4*>(src + 4);
    }
    short8 ah[2], al[2];
#pragma unroll
    for (int mt = 0; mt < 2; mt++) cvt8_hl(araw[mt][0], araw[mt][1], ah[mt], al[mt]);

#pragma unroll
    for (int ntp = 0; ntp < 2; ntp++) {
      short8 bh[2], bl[2];
#pragma unroll
      for (int j = 0; j < 2; j++) {
        const int n = wave * 64 + (ntp * 2 + j) * 16 + i16;
        bh[j] = *reinterpret_cast<const short8*>(WqTh + (size_t)n * DQ + kk + hi4 * 8);
        bl[j] = *reinterpret_cast<const short8*>(WqTl + (size_t)n * DQ + kk + hi4 * 8);
      }
#pragma unroll
      for (int mt = 0; mt < 2; mt++)
#pragma unroll
        for (int j = 0; j < 2; j++) {
          f32x4 a = acc[mt][ntp * 2 + j];
          a = __builtin_amdgcn_mfma_f32_16x16x32_bf16(ah[mt], bh[j], a, 0, 0, 0);
          a = __builtin_amdgcn_mfma_f32_16x16x32_bf16(al[mt], bh[j], a, 0, 0, 0);
          a = __builtin_amdgcn_mfma_f32_16x16x32_bf16(ah[mt], bl[j], a, 0, 0, 0);
          acc[mt][ntp * 2 + j] = a;
        }
    }
  }

  const float scale = 0.0625f;
#pragma unroll
  for (int nt = 0; nt < 4; nt++) {
    const int n = wave * 64 + nt * 16 + i16;
    const float bias = bq[n];
#pragma unroll
    for (int mt = 0; mt < 2; mt++)
#pragma unroll
      for (int r = 0; r < 4; r++) {
        const int m = mbase + mt * 16 + hi4 * 4 + r;
        float x = (acc[mt][nt][r] + bias) * scale;
        unsigned short h, l; split2(x, h, l);
        qzh[(size_t)m * DZ + n] = h;
        qzl[(size_t)m * DZ + n] = l;
      }
  }
}

// ---------------- qk = qz @ Wk^T (3-term split), stored as split bf16 pair ----------------
__global__ __launch_bounds__(256, 4) void qk_kernel(
    const unsigned short* __restrict__ qzh, const unsigned short* __restrict__ qzl,
    const unsigned short* __restrict__ Wkh, const unsigned short* __restrict__ Wkl,
    unsigned short* __restrict__ qkh, unsigned short* __restrict__ qkl)
{
  const int tid = threadIdx.x;
  const int wave = tid >> 6, lane = tid & 63;
  const int i16 = lane & 15, hi4 = lane >> 4;
  const int mbase = blockIdx.x * 32;

  f32x4 acc[2][4];
#pragma unroll
  for (int a = 0; a < 2; a++)
#pragma unroll
    for (int b = 0; b < 4; b++) acc[a][b] = {0.f, 0.f, 0.f, 0.f};

#pragma unroll
  for (int kk = 0; kk < DZ; kk += 32) {
    short8 ah[2], al[2];
#pragma unroll
    for (int mt = 0; mt < 2; mt++) {
      ah[mt] = *reinterpret_cast<const short8*>(qzh + (size_t)(mbase + mt * 16 + i16) * DZ + kk + hi4 * 8);
      al[mt] = *reinterpret_cast<const short8*>(qzl + (size_t)(mbase + mt * 16 + i16) * DZ + kk + hi4 * 8);
    }
#pragma unroll
    for (int ntp = 0; ntp < 2; ntp++) {
      short8 bh[2], bl[2];
#pragma unroll
      for (int j = 0; j < 2; j++) {
        const int n = wave * 64 + (ntp * 2 + j) * 16 + i16;   // x index (row of Wk)
        bh[j] = *reinterpret_cast<const short8*>(Wkh + (size_t)n * DZ + kk + hi4 * 8);
        bl[j] = *reinterpret_cast<const short8*>(Wkl + (size_t)n * DZ + kk + hi4 * 8);
      }
#pragma unroll
      for (int mt = 0; mt < 2; mt++)
#pragma unroll
        for (int j = 0; j < 2; j++) {
          f32x4 a = acc[mt][ntp * 2 + j];
          a = __builtin_amdgcn_mfma_f32_16x16x32_bf16(ah[mt], bh[j], a, 0, 0, 0);
          a = __builtin_amdgcn_mfma_f32_16x16x32_bf16(al[mt], bh[j], a, 0, 0, 0);
          a = __builtin_amdgcn_mfma_f32_16x16x32_bf16(ah[mt], bl[j], a, 0, 0, 0);
          acc[mt][ntp * 2 + j] = a;
        }
    }
  }

#pragma unroll
  for (int nt = 0; nt < 4; nt++) {
    const int n = wave * 64 + nt * 16 + i16;
#pragma unroll
    for (int mt = 0; mt < 2; mt++)
#pragma unroll
      for (int r = 0; r < 4; r++) {
        const int mrow = mbase + mt * 16 + hi4 * 4 + r;
        unsigned short h, l; split2(acc[mt][nt][r], h, l);
        qkh[(size_t)mrow * DK + n] = h;
        qkl[(size_t)mrow * DK + n] = l;
      }
  }
}

// ---------------- attn v7: block/group, k->LDS staging (R7, fast), bpermute P-transpose (R9,
// verified), mbits mask, single-arg bounds (R13, no spill), ONE barrier total ----------------
// S layout: lane (q=q16, h), reg (mt,r) holds S[l=16mt+4h+r][q16].
// PV A-frag elem j (kt): P[l=32kt+8h+j][q16]; pull both mt=2kt,2kt+1 via bpermute from
// src lane q16+16*((2h+(j>=4))&3), select by DEST hb=h>>1 AFTER the permute.
__global__ __launch_bounds__(256) void attn_v7_kernel(
    const float* __restrict__ kmat, const float* __restrict__ vmat,
    const void* __restrict__ mmask, const int* __restrict__ mflagp,
    const int* __restrict__ starts,
    const unsigned short* __restrict__ qkh, const unsigned short* __restrict__ qkl,
    float* __restrict__ out)
{
  const int g = blockIdx.x;
  const int q0 = starts[g], q1 = starts[g + 1];
  if (q0 >= q1) return;

  const int tid = threadIdx.x;
  const int wave = tid >> 6, lane = tid & 63;
  const int q16 = lane & 15, h = lane >> 4;

  __shared__ __align__(16) unsigned short k_lds[CTX * DK];   // 32 KB, XOR-swizzled rows

  // ---- stage k[g] (64x256 f32) -> bf16 LDS, swizzled (all loads issued up-front)
  const float* kg = kmat + (size_t)g * (CTX * DK);
#pragma unroll
  for (int it = 0; it < 8; it++) {
    const int flat = it * 2048 + tid * 8;
    const int row = flat >> 8, col = flat & 255;
    f32x4 f0 = *reinterpret_cast<const f32x4*>(kg + flat);
    f32x4 f1 = *reinterpret_cast<const f32x4*>(kg + flat + 4);
    short8 h8 = cvt8_h(f0, f1);
    const int boff = (row * 512 + col * 2) ^ ((row & 7) << 4);
    *reinterpret_cast<short8*>(reinterpret_cast<char*>(k_lds) + boff) = h8;
  }

  // ---- mask bitmask: bit (mt*4+r) = valid(l = 16mt + 4h + r)
  unsigned int mbits = 0;
  const int mfl = mflagp[0];
#pragma unroll
  for (int mt = 0; mt < 4; mt++)
#pragma unroll
    for (int r = 0; r < 4; r++) {
      const int l = mt * 16 + 4 * h + r;
      bool valid;
      if (mfl) valid = ((const unsigned char*)mmask)[(size_t)g * CTX + l] != 0;
      else     valid = ((const unsigned int*)mmask)[(size_t)g * CTX + l] != 0u;
      mbits |= (valid ? 1u : 0u) << (mt * 4 + r);
    }

  // ---- preload v slice to regs (chunk-invariant, d-split across waves)
  const float* vg = vmat + (size_t)g * (CTX * DV);
  short8 vb[2][4];
#pragma unroll
  for (int kt = 0; kt < 2; kt++)
#pragma unroll
    for (int nt = 0; nt < 4; nt++) {
      const int d = wave * 64 + nt * 16 + q16;
      const float* vcol = vg + (size_t)(kt * 32 + h * 8) * DV + d;
      short8 t;
#pragma unroll
      for (int j = 0; j < 8; j++) t[j] = (short)f2bf_bits(vcol[(size_t)j * DV]);
      vb[kt][nt] = t;
    }

  __syncthreads();   // k_lds ready; read-only hereafter — the only barrier

  const int nchunks = (q1 - q0 + 15) >> 4;

  for (int c = 0; c < nchunks; c++) {
    const int qbase = q0 + c * 16;
    int qrow = qbase + q16; if (qrow > NQ - 1) qrow = NQ - 1;   // clamp, masked at store
    const unsigned short* qh_p = qkh + (size_t)qrow * DK;
    const unsigned short* ql_p = qkl + (size_t)qrow * DK;

    // ---- S: A-frags from swizzled k_lds, B-frags (qk) from global
    f32x4 accs[4];
#pragma unroll
    for (int mt = 0; mt < 4; mt++) accs[mt] = {0.f, 0.f, 0.f, 0.f};
#pragma unroll
    for (int kk = 0; kk < DK; kk += 32) {
      short8 bfh = *reinterpret_cast<const short8*>(qh_p + kk + h * 8);
      short8 bfl = *reinterpret_cast<const short8*>(ql_p + kk + h * 8);
#pragma unroll
      for (int mt = 0; mt < 4; mt++) {
        const int mrow = mt * 16 + q16;
        const int boff = (mrow * 512 + (kk + h * 8) * 2) ^ ((mrow & 7) << 4);
        short8 af = *reinterpret_cast<const short8*>(reinterpret_cast<const char*>(k_lds) + boff);
        accs[mt] = __builtin_amdgcn_mfma_f32_16x16x32_bf16(af, bfh, accs[mt], 0, 0, 0);
        accs[mt] = __builtin_amdgcn_mfma_f32_16x16x32_bf16(af, bfl, accs[mt], 0, 0, 0);
      }
    }

    // ---- mask + softmax over l (16 in-lane + cross-h via shfl_xor 16/32)
    float mx = -3.0e38f;
#pragma unroll
    for (int mt = 0; mt < 4; mt++)
#pragma unroll
      for (int r = 0; r < 4; r++) {
        float s = accs[mt][r] + (((mbits >> (mt * 4 + r)) & 1u) ? 0.0f : -1e30f);
        accs[mt][r] = s;
        mx = fmaxf(mx, s);
      }
    mx = fmaxf(mx, __shfl_xor(mx, 16));
    mx = fmaxf(mx, __shfl_xor(mx, 32));
    float sum = 0.f;
#pragma unroll
    for (int mt = 0; mt < 4; mt++)
#pragma unroll
      for (int r = 0; r < 4; r++) {
        float p = __expf(accs[mt][r] - mx);
        accs[mt][r] = p;
        sum += p;
      }
    sum += __shfl_xor(sum, 16);
    sum += __shfl_xor(sum, 32);
    const float inv = 1.0f / sum;

    // ---- pack P (hi+lo) into u32 pairs: w0*[mt]=(r0,r1), w1*[mt]=(r2,r3)
    unsigned int w0h[4], w1h[4], w0l[4], w1l[4];
#pragma unroll
    for (int mt = 0; mt < 4; mt++) {
      unsigned short hh[4], ll[4];
#pragma unroll
      for (int r = 0; r < 4; r++) {
        float pn = accs[mt][r] * inv;
        split2(pn, hh[r], ll[r]);
      }
      w0h[mt] = (unsigned int)hh[0] | ((unsigned int)hh[1] << 16);
      w1h[mt] = (unsigned int)hh[2] | ((unsigned int)hh[3] << 16);
      w0l[mt] = (unsigned int)ll[0] | ((unsigned int)ll[1] << 16);
      w1l[mt] = (unsigned int)ll[2] | ((unsigned int)ll[3] << 16);
    }

    // ---- cross-lane permute: pull BOTH mt candidates, select by DEST hb after (R9-verified)
    const int hb = h >> 1;
    const int sl0 = (q16 + 16 * ((2 * h) & 3)) << 2;
    const int sl1 = (q16 + 16 * ((2 * h + 1) & 3)) << 2;
    short8 pah[2], pal[2];
#pragma unroll
    for (int kt = 0; kt < 2; kt++) {
      u32x4 bh_, bl_;
      unsigned int e, o;
      e = (unsigned int)__builtin_amdgcn_ds_bpermute(sl0, (int)w0h[2 * kt]);
      o = (unsigned int)__builtin_amdgcn_ds_bpermute(sl0, (int)w0h[2 * kt + 1]);
      bh_[0] = hb ? o : e;
      e = (unsigned int)__builtin_amdgcn_ds_bpermute(sl0, (int)w1h[2 * kt]);
      o = (unsigned int)__builtin_amdgcn_ds_bpermute(sl0, (int)w1h[2 * kt + 1]);
      bh_[1] = hb ? o : e;
      e = (unsigned int)__builtin_amdgcn_ds_bpermute(sl1, (int)w0h[2 * kt]);
      o = (unsigned int)__builtin_amdgcn_ds_bpermute(sl1, (int)w0h[2 * kt + 1]);
      bh_[2] = hb ? o : e;
      e = (unsigned int)__builtin_amdgcn_ds_bpermute(sl1, (int)w1h[2 * kt]);
      o = (unsigned int)__builtin_amdgcn_ds_bpermute(sl1, (int)w1h[2 * kt + 1]);
      bh_[3] = hb ? o : e;

      e = (unsigned int)__builtin_amdgcn_ds_bpermute(sl0, (int)w0l[2 * kt]);
      o = (unsigned int)__builtin_amdgcn_ds_bpermute(sl0, (int)w0l[2 * kt + 1]);
      bl_[0] = hb ? o : e;
      e = (unsigned int)__builtin_amdgcn_ds_bpermute(sl0, (int)w1l[2 * kt]);
      o = (unsigned int)__builtin_amdgcn_ds_bpermute(sl0, (int)w1l[2 * kt + 1]);
      bl_[1] = hb ? o : e;
      e = (unsigned int)__builtin_amdgcn_ds_bpermute(sl1, (int)w0l[2 * kt]);
      o = (unsigned int)__builtin_amdgcn_ds_bpermute(sl1, (int)w0l[2 * kt + 1]);
      bl_[2] = hb ? o : e;
      e = (unsigned int)__builtin_amdgcn_ds_bpermute(sl1, (int)w1l[2 * kt]);
      o = (unsigned int)__builtin_amdgcn_ds_bpermute(sl1, (int)w1l[2 * kt + 1]);
      bl_[3] = hb ? o : e;

      pah[kt] = __builtin_bit_cast(short8, bh_);
      pal[kt] = __builtin_bit_cast(short8, bl_);
    }

    // ---- PV with v in regs
    f32x4 acco[4];
#pragma unroll
    for (int nt = 0; nt < 4; nt++) acco[nt] = {0.f, 0.f, 0.f, 0.f};
#pragma unroll
    for (int kt = 0; kt < 2; kt++)
#pragma unroll
      for (int nt = 0; nt < 4; nt++) {
        acco[nt] = __builtin_amdgcn_mfma_f32_16x16x32_bf16(pah[kt], vb[kt][nt], acco[nt], 0, 0, 0);
        acco[nt] = __builtin_amdgcn_mfma_f32_16x16x32_bf16(pal[kt], vb[kt][nt], acco[nt], 0, 0, 0);
      }

#pragma unroll
    for (int nt = 0; nt < 4; nt++) {
      const int d = wave * 64 + nt * 16 + q16;
#pragma unroll
      for (int r = 0; r < 4; r++) {
        const int qrow2 = qbase + h * 4 + r;
        if (qrow2 < q1)
          out[(size_t)qrow2 * DV + d] = acco[nt][r];
      }
    }
  }
}

extern "C" void kernel_launch(void* const* d_in, const int* in_sizes, int n_in,
                              void* d_out, int out_size, void* d_ws, size_t ws_size,
                              hipStream_t stream) {
  const float* q  = (const float*)d_in[0];
  const float* k  = (const float*)d_in[1];
  const float* v  = (const float*)d_in[2];
  const void*  m  = d_in[3];
  const int* gidx = (const int*)d_in[4];
  const float* Wq = (const float*)d_in[5];
  const float* bq = (const float*)d_in[6];
  const float* Wk = (const float*)d_in[7];   // bk dropped: per-query constant cancels in softmax
  float* out = (float*)d_out;

  char* ws = (char*)d_ws;
  unsigned short* qzh  = (unsigned short*)(ws);                   // 4 MB
  unsigned short* qzl  = (unsigned short*)(ws + 4194304);         // 4 MB
  unsigned short* qkh  = (unsigned short*)(ws + 8388608);         // 4 MB
  unsigned short* qkl  = (unsigned short*)(ws + 12582912);        // 4 MB
  unsigned short* WqTh = (unsigned short*)(ws + 16777216);        // 256 KB
  unsigned short* WqTl = (unsigned short*)(ws + 17039360);        // 256 KB
  unsigned short* Wkh  = (unsigned short*)(ws + 17301504);        // 128 KB
  unsigned short* Wkl  = (unsigned short*)(ws + 17432576);        // 128 KB
  int* starts          = (int*)(ws + 17563648);                   // 2049*4
  int* mflag           = (int*)(ws + 17571844);                   // 4 B

  hipLaunchKernelGGL(prep_kernel, dim3(777), dim3(256), 0, stream,
                     Wq, Wk, gidx, WqTh, WqTl, Wkh, Wkl, starts, mflag);
  hipLaunchKernelGGL(maskscan_kernel, dim3(128), dim3(256), 0, stream,
                     (const unsigned int*)m, mflag);
  hipLaunchKernelGGL(qz_kernel, dim3(NQ / 32), dim3(256), 0, stream,
                     q, bq, WqTh, WqTl, qzh, qzl);
  hipLaunchKernelGGL(qk_kernel, dim3(NQ / 32), dim3(256), 0, stream,
                     qzh, qzl, Wkh, Wkl, qkh, qkl);
  hipLaunchKernelGGL(attn_v7_kernel, dim3(NG), dim3(256), 0, stream,
                     k, v, m, (const int*)mflag, starts, qkh, qkl, out);
}